// Round 7
// baseline (22680.936 us; speedup 1.0000x reference)
//
#include <hip/hip_runtime.h>

// LSTM B=1024 T=512 H=256 (input_size=1, output_size=1) on MI355X.
// R7: use ALL 256 CUs (R4-R6 used 64: device MfmaUtil 7% but per-CU matrix
// pipe ~33% -> the idle 192 CUs were the real headroom).
// 256 blocks x 256 thr (4 waves, 1/SIMD). Group g = blocks {g,g+64,g+128,g+192}
// (same XCD under bid%8 round-robin -- locality heuristic only). Group owns 16
// batch rows; block j owns hidden units [64j,64j+64); wave v owns the i/f/g/o
// tiles of units [64j+16v,+16) -> ALL W_hh register-resident (128 VGPRs, no
// streaming, no W LDS). Per step:
//   read h[16,256] bf16 (8 KB) from group global dbuf (L2) -> A-frags
//   32 MFMAs/SIMD -> gates (lane-local c/h) -> write own 2 KB h quarter
//   release fence -> group arrival counter (monotonic atomicAdd, device scope)
//   -> tid0 spin -> acquire fence (invalidates L1) -> next step.
// x staged in LDS (32 KB) so per-step x reads survive the L1 invalidation.
// ws: [0,1MB) h dbuf (2 x 64 groups x 16 x 256 bf16), [1MB,+4KB) counters;
// zeroed via hipMemsetAsync each launch (h(0)=0 + monotonic ctr start).

#define TT 512
#define GROUPS 64
#define NBLK 256
#define THREADS 256
#define HG_ELEMS (16 * 256)                 // per group per buffer (bf16)
#define HG_BYTES (2ull * GROUPS * HG_ELEMS * 2)   // 1 MiB
#define CTR_OFF HG_BYTES

typedef float v4f __attribute__((ext_vector_type(4)));
typedef unsigned int v4u __attribute__((ext_vector_type(4)));
typedef unsigned short v8us __attribute__((ext_vector_type(8)));
typedef __bf16 v8bf __attribute__((ext_vector_type(8)));

__device__ __forceinline__ unsigned short f2bf(float f) {
    unsigned int u = __builtin_bit_cast(unsigned int, f);
    u += 0x7fffu + ((u >> 16) & 1u);   // RNE
    return (unsigned short)(u >> 16);
}
__device__ __forceinline__ float bf2f(unsigned short s) {
    unsigned int u = ((unsigned int)s) << 16;
    return __builtin_bit_cast(float, u);
}
__device__ __forceinline__ float fsigmoid(float x) {
    float e = exp2f(x * -1.44269504f);
    return __builtin_amdgcn_rcpf(1.0f + e);
}
__device__ __forceinline__ float ftanh(float x) {
    float e = exp2f(x * 2.88539008f);
    return 1.0f - 2.0f * __builtin_amdgcn_rcpf(1.0f + e);
}

__global__ __launch_bounds__(THREADS, 1)
void lstm_kernel(const float* __restrict__ x,
                 const float* __restrict__ W_ih,
                 const float* __restrict__ W_hh,
                 const float* __restrict__ b_ih,
                 const float* __restrict__ b_hh,
                 const float* __restrict__ W_lin,
                 const float* __restrict__ b_lin,
                 unsigned short* __restrict__ hglob,
                 unsigned int* __restrict__ ctr,
                 float* __restrict__ out) {
    __shared__ float xT[TT * 16];     // 32 KB: xT[t*16 + m]
    __shared__ float part[THREADS];   // 1 KB (epilogue)

    const int tid  = threadIdx.x;
    const int lane = tid & 63;
    const int v    = tid >> 6;        // wave 0..3 -> unit sub-segment
    const int l4   = lane & 15;
    const int quad = lane >> 4;
    const int g    = blockIdx.x & 63;       // group = batch slice
    const int j    = blockIdx.x >> 6;       // quarter of hidden units
    const int r0   = g * 16;                // batch rows [r0, r0+16)

    // ---- W_hh -> 32 register-resident B-fragments (bf16), i/f/g/o of units
    //      [64j+16v, +16). Lane holds row n = Tn*16+l4, k = kc*32+quad*8+.. ----
    v8bf wfrag[4][8];
#pragma unroll
    for (int G = 0; G < 4; ++G) {
        int Tn = 16 * G + 4 * j + v;
        const float* wr = W_hh + (size_t)(Tn * 16 + l4) * 256;
#pragma unroll
        for (int kc = 0; kc < 8; ++kc) {
            int k0 = kc * 32 + quad * 8;
            v8us u;
#pragma unroll
            for (int e = 0; e < 8; ++e) u[e] = f2bf(wr[k0 + e]);
            wfrag[G][kc] = __builtin_bit_cast(v8bf, u);
        }
    }

    // Per-lane gate constants (unit n_ = 64j + 16v + l4)
    const int n_ = 64 * j + 16 * v + l4;
    float wi[4], bb[4];
#pragma unroll
    for (int G = 0; G < 4; ++G) {
        wi[G] = W_ih[G * 256 + n_];
        bb[G] = b_ih[G * 256 + n_] + b_hh[G * 256 + n_];
    }

    // Stage x rows r0..r0+15 into LDS, transposed (coalesced along t)
    for (int i = tid; i < 16 * TT; i += THREADS) {
        int m = i >> 9, t = i & 511;
        xT[t * 16 + m] = x[(size_t)(r0 + m) * TT + t];
    }
    __syncthreads();

    unsigned short* __restrict__ hg0 = hglob + (size_t)g * HG_ELEMS;                       // buf 0
    unsigned short* __restrict__ hg1 = hglob + (size_t)(GROUPS + g) * HG_ELEMS;            // buf 1
    unsigned int* __restrict__ ctrg = ctr + g * 16;   // 64B-padded per group

    float c0 = 0.f, c1 = 0.f, c2 = 0.f, c3 = 0.f;

    for (int t = 0; t < TT; ++t) {
        const unsigned short* hb = (t & 1) ? hg1 : hg0;
        unsigned short* hn = (t & 1) ? hg0 : hg1;

        // A-frags: lane reads h[m=l4][k = kc*32 + quad*8 ..+8] (16B each).
        // Issue all 8 loads up front; INITG VALU overlaps the L2 latency.
        v8bf afrag[8];
#pragma unroll
        for (int kc = 0; kc < 8; ++kc)
            afrag[kc] = __builtin_bit_cast(v8bf,
                *(const v4u*)(hb + l4 * 256 + kc * 32 + quad * 8));

        // acc init = x*W_ih + bias (rows m = quad*4 + r)
        v4f ai, af2, ag, ao;
#pragma unroll
        for (int r = 0; r < 4; ++r) {
            float xv = xT[t * 16 + quad * 4 + r];
            ai[r]  = xv * wi[0] + bb[0];
            af2[r] = xv * wi[1] + bb[1];
            ag[r]  = xv * wi[2] + bb[2];
            ao[r]  = xv * wi[3] + bb[3];
        }

        // 32 MFMAs: 4 independent chains of 8
#pragma unroll
        for (int kc = 0; kc < 8; ++kc) {
            v8bf a = afrag[kc];
            ai  = __builtin_amdgcn_mfma_f32_16x16x32_bf16(a, wfrag[0][kc], ai,  0, 0, 0);
            af2 = __builtin_amdgcn_mfma_f32_16x16x32_bf16(a, wfrag[1][kc], af2, 0, 0, 0);
            ag  = __builtin_amdgcn_mfma_f32_16x16x32_bf16(a, wfrag[2][kc], ag,  0, 0, 0);
            ao  = __builtin_amdgcn_mfma_f32_16x16x32_bf16(a, wfrag[3][kc], ao,  0, 0, 0);
        }

        // gates + state update (lane-local: unit n_, rows m = quad*4+r);
        // write own h quarter to the next buffer
#pragma unroll
        for (int r = 0; r < 4; ++r) {
            float gi = fsigmoid(ai[r]);
            float gf = fsigmoid(af2[r]);
            float gg = ftanh(ag[r]);
            float go = fsigmoid(ao[r]);
            float cp = (r == 0) ? c0 : (r == 1) ? c1 : (r == 2) ? c2 : c3;
            float cn = gf * cp + gi * gg;
            if (r == 0) c0 = cn; else if (r == 1) c1 = cn;
            else if (r == 2) c2 = cn; else c3 = cn;
            hn[(quad * 4 + r) * 256 + n_] = f2bf(go * ftanh(cn));
        }

        // ---- group barrier: release own writes, arrive, spin, acquire ----
        __threadfence();            // drain + make h stores visible (agent)
        __syncthreads();            // all waves of this block done
        if (tid == 0) {
            __hip_atomic_fetch_add(ctrg, 1u, __ATOMIC_RELAXED,
                                   __HIP_MEMORY_SCOPE_AGENT);
            unsigned tgt = 4u * (unsigned)(t + 1);
            while (__hip_atomic_load(ctrg, __ATOMIC_RELAXED,
                                     __HIP_MEMORY_SCOPE_AGENT) < tgt)
                __builtin_amdgcn_s_sleep(1);
        }
        __syncthreads();
        __threadfence();            // acquire: invalidate L1 before h reads
    }

    // Epilogue: block j==0 of each group writes out[r0..r0+16).
    // Final h is in buffer 0 (t=511 wrote hg0); barrier above guarantees
    // visibility of all four quarters.
    if (j == 0) {
        int m = tid >> 4, s = tid & 15;
        float p = 0.0f;
#pragma unroll
        for (int jj = 0; jj < 16; ++jj) {
            int u = s * 16 + jj;
            p += bf2f(hg0[m * 256 + u]) * W_lin[u];
        }
        part[tid] = p;
        __syncthreads();
        if (tid < 16) {
            float sum = 0.0f;
#pragma unroll
            for (int s2 = 0; s2 < 16; ++s2) sum += part[tid * 16 + s2];
            out[r0 + tid] = sum + b_lin[0];
        }
    }
}

extern "C" void kernel_launch(void* const* d_in, const int* in_sizes, int n_in,
                              void* d_out, int out_size, void* d_ws, size_t ws_size,
                              hipStream_t stream) {
    const float* x     = (const float*)d_in[0];
    const float* W_ih  = (const float*)d_in[1];
    const float* W_hh  = (const float*)d_in[2];
    const float* b_ih  = (const float*)d_in[3];
    const float* b_hh  = (const float*)d_in[4];
    const float* W_lin = (const float*)d_in[5];
    const float* b_lin = (const float*)d_in[6];

    unsigned short* hglob = (unsigned short*)d_ws;                     // 1 MiB
    unsigned int*   ctr   = (unsigned int*)((char*)d_ws + CTR_OFF);    // 4 KiB

    // h(0)=0 and monotonic counters start at 0 (ws is poisoned 0xAA each call)
    hipMemsetAsync(d_ws, 0, HG_BYTES + GROUPS * 16 * sizeof(unsigned int), stream);

    lstm_kernel<<<NBLK, THREADS, 0, stream>>>(x, W_ih, W_hh, b_ih, b_hh,
                                              W_lin, b_lin, hglob, ctr,
                                              (float*)d_out);
}

// Round 8
// 1836.530 us; speedup vs baseline: 12.3499x; 12.3499x over previous
//
#include <hip/hip_runtime.h>

// LSTM B=1024 T=512 H=256 (input_size=1, output_size=1) on MI355X.
// R8 = R4 structure (proven best, spill-free) + verified-good R6 parts:
//  - 64 blocks (1/CU) x 512 thr (8 waves, 2/SIMD). Wave w owns N-tiles of
//    hidden segments w, w+8: i,f tiles in regs/AGPRs (128), g tiles in LDS
//    (16 tiles = 128 KB), o tiles streamed from L2 via ONE rotating 32-reg
//    buffer (each load has >= half a step of latency cover -- R6's 4-slot
//    rotation exposed ~150cy/refill and regressed; R4's scheme did not).
//  - hbuf XOR swizzle (R6-verified: conflicts 8.4M -> 3k).
//  - LDS-only barrier `s_waitcnt lgkmcnt(0); s_barrier` (R6-verified): h is
//    DS-only so lgkmcnt covers it; in-flight global o/x prefetches are NOT
//    drained (R4's __syncthreads drained vmcnt(0) 512 times).
//  - x for t+1 prefetched mid-step, rides the barrier.
// R7 lesson: no per-step cross-block sync (device fences = L2 flush storms).

#define HID 256
#define TT 512
#define BROWS 16
#define NBLK 64
#define THREADS 512

typedef float v4f __attribute__((ext_vector_type(4)));
typedef unsigned int v4u __attribute__((ext_vector_type(4)));
typedef __bf16 v8bf __attribute__((ext_vector_type(8)));

__device__ __forceinline__ unsigned short f2bf(float f) {
    unsigned int u = __builtin_bit_cast(unsigned int, f);
    u += 0x7fffu + ((u >> 16) & 1u);   // RNE
    return (unsigned short)(u >> 16);
}
__device__ __forceinline__ float bf2f(unsigned short s) {
    unsigned int u = ((unsigned int)s) << 16;
    return __builtin_bit_cast(float, u);
}
__device__ __forceinline__ float fsigmoid(float x) {
    float e = exp2f(x * -1.44269504f);
    return __builtin_amdgcn_rcpf(1.0f + e);
}
__device__ __forceinline__ float ftanh(float x) {
    float e = exp2f(x * 2.88539008f);
    return 1.0f - 2.0f * __builtin_amdgcn_rcpf(1.0f + e);
}

// W_hh fp32 [1024][256] -> bf16 fragment order:
// Wbf[((Tn*8+kc)*64+lane)*8 + j] = bf16(W_hh[16*Tn+(lane&15)][32*kc+(lane>>4)*8+j])
__global__ void wconv_kernel(const float* __restrict__ Whh,
                             unsigned short* __restrict__ Wbf) {
    int tid = blockIdx.x * blockDim.x + threadIdx.x;   // 0..32767
    int lane = tid & 63;
    int frag = tid >> 6;
    int Tn = frag >> 3;
    int kc = frag & 7;
    int n  = Tn * 16 + (lane & 15);
    int kb = kc * 32 + (lane >> 4) * 8;
    const float* src = Whh + (size_t)n * HID + kb;
    unsigned short* dst = Wbf + (size_t)tid * 8;
#pragma unroll
    for (int j = 0; j < 8; ++j) dst[j] = f2bf(src[j]);
}

#define MFMA8(ACC, BARR, BOFF)                                               \
    _Pragma("unroll")                                                        \
    for (int kc = 0; kc < 8; ++kc)                                           \
        ACC = __builtin_amdgcn_mfma_f32_16x16x32_bf16(afrag[kc],             \
                  BARR[(BOFF) + kc], ACC, 0, 0, 0);

// LDS-resident g-tile, slot = w*2 + S (lane-contiguous: conflict-free)
#define LDSTILE(ACC, SLOT)                                                   \
    { v8bf bl_[8];                                                           \
      _Pragma("unroll")                                                      \
      for (int kc = 0; kc < 8; ++kc)                                         \
          bl_[kc] = __builtin_bit_cast(v8bf, *(const v4u*)(Wlds +            \
                      ((size_t)(((SLOT) * 8 + kc) * 64 + lane)) * 8));       \
      MFMA8(ACC, bl_, 0) }

// stream a whole tile by absolute tile index TN into SB (32 regs)
#define SLOADT(SB, TN)                                                       \
    _Pragma("unroll")                                                        \
    for (int kc = 0; kc < 8; ++kc)                                           \
        SB[kc] = __builtin_bit_cast(v8bf,                                    \
                   Wv[((size_t)(TN) * 8 + kc) * 64 + lane]);

#define INITG(S, AI, AF, AG, AO)                                             \
    { int nb = 16 * (w + 8 * (S)) + l4;                                      \
      float w0 = gw[nb],       b0 = gb[nb];                                  \
      float w1 = gw[256 + nb], b1 = gb[256 + nb];                            \
      float w2 = gw[512 + nb], b2 = gb[512 + nb];                            \
      float w3 = gw[768 + nb], b3 = gb[768 + nb];                            \
      _Pragma("unroll")                                                      \
      for (int r = 0; r < 4; ++r) {                                          \
          AI[r] = xv[r] * w0 + b0; AF[r] = xv[r] * w1 + b1;                  \
          AG[r] = xv[r] * w2 + b2; AO[r] = xv[r] * w3 + b3; } }

// swizzled h-write: unit n_ = 16*(w+8S)+l4, row m = quad*4+r
#define GATES(S, AI, AF, AG, AO)                                             \
    { int n_ = 16 * (w + 8 * (S)) + l4;                                      \
      int gn = n_ >> 3;                                                      \
      _Pragma("unroll")                                                      \
      for (int r = 0; r < 4; ++r) {                                          \
        float gi = fsigmoid(AI[r]);                                          \
        float gf = fsigmoid(AF[r]);                                          \
        float gg = ftanh(AG[r]);                                             \
        float go = fsigmoid(AO[r]);                                          \
        float cn = gf * c_st[(S) * 4 + r] + gi * gg;                         \
        c_st[(S) * 4 + r] = cn;                                              \
        int m = quad * 4 + r;                                                \
        hn_[m * 256 + ((gn ^ m) & 31) * 8 + (n_ & 7)] = f2bf(go * ftanh(cn));\
      } }

__global__ __launch_bounds__(THREADS, 2)
void lstm_kernel(const float* __restrict__ x,
                 const float* __restrict__ W_ih,
                 const float* __restrict__ b_ih,
                 const float* __restrict__ b_hh,
                 const float* __restrict__ W_lin,
                 const float* __restrict__ b_lin,
                 const unsigned short* __restrict__ Wbf,
                 float* __restrict__ out) {
    __shared__ __align__(16) unsigned short Wlds[16 * 8 * 64 * 8];   // 128 KB (g-tiles)
    __shared__ __align__(16) unsigned short hbuf[2][BROWS * 256];    // 16 KB, XOR-swizzled
    __shared__ float gw[1024];                                       // 4 KB
    __shared__ float gb[1024];                                       // 4 KB
    __shared__ float part[THREADS];                                  // 2 KB

    const int tid  = threadIdx.x;
    const int lane = tid & 63;
    const int w    = tid >> 6;      // wave 0..7
    const int l4   = lane & 15;
    const int quad = lane >> 4;
    const int r0   = blockIdx.x * BROWS;

    // gate consts -> LDS
    for (int i = tid; i < 1024; i += THREADS) {
        gw[i] = W_ih[i];
        gb[i] = b_ih[i] + b_hh[i];
    }
    // h(0) = 0
    for (int i = tid; i < BROWS * 256; i += THREADS) {
        hbuf[0][i] = 0;
        hbuf[1][i] = 0;
    }

    const v4u* __restrict__ Wv = (const v4u*)Wbf;   // frag idx (Tn*8+kc)*64+lane

    // reg/AGPR-resident i,f tiles: [0]=i,S0(Tn=w) [1]=f,S0(16+w) [2]=i,S1(8+w) [3]=f,S1(24+w)
    v8bf wres[32];
    {
        const int tns[4] = {w, 16 + w, 8 + w, 24 + w};
#pragma unroll
        for (int qq = 0; qq < 4; ++qq)
#pragma unroll
            for (int kc = 0; kc < 8; ++kc)
                wres[qq * 8 + kc] = __builtin_bit_cast(v8bf,
                    Wv[((size_t)(tns[qq]) * 8 + kc) * 64 + lane]);
    }
    // LDS-resident g-tiles: slot w*2+S <- Tn = 32 + w + 8*S
#pragma unroll
    for (int S = 0; S < 2; ++S) {
        int Tn = 32 + w + 8 * S;
        int slot = w * 2 + S;
#pragma unroll
        for (int kc = 0; kc < 8; ++kc) {
            v4u d = Wv[((size_t)Tn * 8 + kc) * 64 + lane];
            *(v4u*)(Wlds + ((size_t)((slot * 8 + kc) * 64 + lane)) * 8) = d;
        }
    }
    __syncthreads();

    float c_st[8];
#pragma unroll
    for (int i = 0; i < 8; ++i) c_st[i] = 0.0f;

    // single rotating o-tile stream buffer; prologue: o,S0 (Tn = 48+w)
    v8bf sb[8];
    SLOADT(sb, 48 + w)

    // x for t=0 (rows quad*4+r; lane-uniform across l4 -> broadcast loads)
    v4f xv;
#pragma unroll
    for (int r = 0; r < 4; ++r)
        xv[r] = x[(size_t)(r0 + quad * 4 + r) * TT];

    int cur = 0;
    for (int t = 0; t < TT; ++t) {
        const unsigned short* hb = hbuf[cur];
        unsigned short* hn_ = hbuf[cur ^ 1];

        // A-frags, swizzled: row l4, logical granule kc*4+quad at pos ^ l4
        v8bf afrag[8];
#pragma unroll
        for (int kc = 0; kc < 8; ++kc)
            afrag[kc] = __builtin_bit_cast(v8bf, *(const v4u*)(
                hb + l4 * 256 + (((kc * 4 + quad) ^ l4) & 31) * 8));

        // ---- group S=0: i,f regs; g LDS; o = sb (prefetched last step) ----
        {
            v4f ai, af2, ag, ao;
            INITG(0, ai, af2, ag, ao)
            MFMA8(ao, sb, 0)                // o,S0
            SLOADT(sb, 56 + w)              // o,S1: consumed ~half a step later
            MFMA8(ai, wres, 0)              // i,S0
            MFMA8(af2, wres, 8)             // f,S0
            LDSTILE(ag, w * 2 + 0)          // g,S0
            GATES(0, ai, af2, ag, ao)
        }
        // ---- group S=1 ----
        {
            v4f ai, af2, ag, ao;
            INITG(1, ai, af2, ag, ao)
            // x prefetch for t+1 (xv dead after INITG); rides the barrier
            {
                int tn = (t + 1 < TT) ? (t + 1) : t;
#pragma unroll
                for (int r = 0; r < 4; ++r)
                    xv[r] = x[(size_t)(r0 + quad * 4 + r) * TT + tn];
            }
            MFMA8(ao, sb, 0)                // o,S1
            SLOADT(sb, 48 + w)              // o,S0 for t+1: rides the barrier
            MFMA8(ai, wres, 16)             // i,S1
            MFMA8(af2, wres, 24)            // f,S1
            LDSTILE(ag, w * 2 + 1)          // g,S1
            GATES(1, ai, af2, ag, ao)
        }

        // LDS-only barrier: drain DS (h-writes) but NOT vmcnt -> o/x prefetch
        // stays in flight across the step boundary.
        asm volatile("s_waitcnt lgkmcnt(0)\n\ts_barrier" ::: "memory");
        cur ^= 1;
    }

    // Epilogue: out[b] = h_final . W_lin + b_lin (swizzled read-back)
    {
        int rrow = tid >> 5, s5 = tid & 31;            // row 0..15, unit-granule 0..31
        int pos = (s5 ^ rrow) & 31;
        float p = 0.0f;
#pragma unroll
        for (int jj = 0; jj < 8; ++jj) {
            int j = s5 * 8 + jj;
            p += bf2f(hbuf[cur][rrow * 256 + pos * 8 + jj]) * W_lin[j];
        }
        part[tid] = p;
    }
    __syncthreads();
    if (tid < 16) {
        float sum = 0.0f;
#pragma unroll
        for (int s = 0; s < 32; ++s) sum += part[tid * 32 + s];
        out[r0 + tid] = sum + b_lin[0];
    }
}

extern "C" void kernel_launch(void* const* d_in, const int* in_sizes, int n_in,
                              void* d_out, int out_size, void* d_ws, size_t ws_size,
                              hipStream_t stream) {
    const float* x     = (const float*)d_in[0];
    const float* W_ih  = (const float*)d_in[1];
    const float* W_hh  = (const float*)d_in[2];
    const float* b_ih  = (const float*)d_in[3];
    const float* b_hh  = (const float*)d_in[4];
    const float* W_lin = (const float*)d_in[5];
    const float* b_lin = (const float*)d_in[6];
    unsigned short* Wbf = (unsigned short*)d_ws;   // 512 KB

    wconv_kernel<<<128, 256, 0, stream>>>(W_hh, Wbf);
    lstm_kernel<<<NBLK, THREADS, 0, stream>>>(x, W_ih, b_ih, b_hh, W_lin, b_lin,
                                              Wbf, (float*)d_out);
}